// Round 11
// baseline (2311.765 us; speedup 1.0000x reference)
//
#include <hip/hip_runtime.h>

typedef _Float16 half8 __attribute__((ext_vector_type(8)));
typedef _Float16 half4_ __attribute__((ext_vector_type(4)));
typedef float f32x4 __attribute__((ext_vector_type(4)));

namespace {
constexpr int kB = 2048;
constexpr int kT = 72;
constexpr int kI = 200;
constexpr int kH = 200;
constexpr int kO = 53;
constexpr int kG = 600;      // 3*kH
constexpr int BT = 16;       // batch rows per WG
constexpr int NWG = kB / BT; // 128
constexpr int KS = 7;        // K slices of 32 covering 224 (200 padded)
constexpr int MT2 = 39;      // 13 jblocks x 3 gates (r,z,n interleaved tiles)
constexpr int PERM2 = MT2 * KS * 64; // 17472 lane-rows per matrix

// ws layout (float offsets). Kernel order: transpose2 -> input -> frags -> main.
// frags overwrite the prep-only WIH1T/FCINT region (read only by prep_input).
constexpr int XW1    = 0;          // [2048][600] emb@Wih1^T + bih1
constexpr int WIH1T  = 1228800;    // [200][600] Wih1^T (prep_input only)
constexpr int FCINT  = 1348800;    // [200][200] fc_in_W^T (prep_input only)
constexpr int F0     = 1228800;    // fp16 A-frags: hh1, ih2, hh2, ih3, hh3 (after prep_input)
constexpr int FSZ2   = 69888;      // floats per frag matrix (39*7*64*8 halves / 2)
constexpr int FHEAD  = F0 + 5 * FSZ2; // head frags (4 tiles)

// output offsets (floats)
constexpr int OH1 = kB * kT * kO;  // 7815168
constexpr int OH2 = OH1 + kB * kH;
constexpr int OH3 = OH2 + kB * kH;
}

__device__ __forceinline__ float sig_(float x) { return 1.0f / (1.0f + __expf(-x)); }
__device__ __forceinline__ float tanh_(float x) {
    return 1.0f - 2.0f / (__expf(2.0f * x) + 1.0f);
}

// barrier draining LDS only; in-flight global weight loads (vmcnt) survive.
__device__ __forceinline__ void barx() {
    asm volatile("s_waitcnt lgkmcnt(0)\n\ts_barrier" ::: "memory");
}

// ---------------- prep kernels (identical to validated R6) ----------------

__global__ __launch_bounds__(256) void prep_transpose2(
    const float* __restrict__ Wih1, const float* __restrict__ fciW,
    float* __restrict__ ws) {
    int idx = blockIdx.x * 256 + threadIdx.x;
    if (idx < 120000) {
        int k = idx / kG, c = idx - k * kG;
        ws[WIH1T + idx] = Wih1[c * kI + k];
    } else {
        int i = idx - 120000;
        if (i < 40000) {
            int k = i / kH, h = i - k * kH;
            ws[FCINT + i] = fciW[h * kI + k];
        }
    }
}

__global__ __launch_bounds__(256) void prep_input(
    const float* __restrict__ enc,
    const float* __restrict__ bn_g, const float* __restrict__ bn_b,
    const float* __restrict__ bn_m, const float* __restrict__ bn_v,
    const float* __restrict__ fcib, const float* __restrict__ bih1,
    float* ws) {
    __shared__ float xh[kI];
    __shared__ float emb[kH];
    const int b = blockIdx.x, tid = threadIdx.x;
    const float* fcInT = ws + FCINT;
    const float* Wih1T = ws + WIH1T;
    if (tid < kI) {
        float x = enc[b * kI + tid];
        xh[tid] = (x - bn_m[tid]) * rsqrtf(bn_v[tid] + 1e-5f) * bn_g[tid] + bn_b[tid];
    }
    __syncthreads();
    if (tid < kH) {
        float s = fcib[tid];
        for (int k = 0; k < kI; ++k) s = fmaf(xh[k], fcInT[k * kH + tid], s);
        emb[tid] = fmaxf(s, 0.0f);
    }
    __syncthreads();
    for (int c = tid; c < kG; c += 256) {
        float s = bih1[c];
        for (int k = 0; k < kH; ++k) s = fmaf(emb[k], Wih1T[k * kG + c], s);
        ws[XW1 + b * kG + c] = s;
    }
}

// pack fp16 MFMA A-fragments, gate-triplet tile order: mt = 3*b + g
__global__ __launch_bounds__(256) void prep_frags(
    const float* __restrict__ Whh1, const float* __restrict__ Wih2,
    const float* __restrict__ Whh2, const float* __restrict__ Wih3,
    const float* __restrict__ Whh3, const float* __restrict__ fcoW,
    float* __restrict__ ws) {
    int idx = blockIdx.x * 256 + threadIdx.x;
    if (idx < 5 * PERM2) {
        int m = idx / PERM2, rem = idx - m * PERM2;
        const float* src;
        switch (m) {
            case 0: src = Whh1; break;
            case 1: src = Wih2; break;
            case 2: src = Whh2; break;
            case 3: src = Wih3; break;
            default: src = Whh3; break;
        }
        int lane = rem & 63;
        int tmp = rem >> 6;
        int ks = tmp % KS;
        int mt = tmp / KS;
        int b = mt / 3, g = mt - 3 * b;
        int rt = b * 16 + (lane & 15);
        int row = g * kH + rt;
        int k0 = ks * 32 + (lane >> 4) * 8;
        half8 v;
        #pragma unroll
        for (int j = 0; j < 8; ++j) {
            int k = k0 + j;
            v[j] = (_Float16)((rt < kH && k < kH) ? src[row * kH + k] : 0.0f);
        }
        *(half8*)((_Float16*)ws + 2LL * (F0 + m * FSZ2) + (long long)rem * 8) = v;
    } else {
        int rem = idx - 5 * PERM2;
        if (rem >= 4 * KS * 64) return;
        int lane = rem & 63;
        int tmp = rem >> 6;
        int ks = tmp % KS;
        int mt = tmp / KS;
        int row = mt * 16 + (lane & 15);
        int k0 = ks * 32 + (lane >> 4) * 8;
        half8 v;
        #pragma unroll
        for (int j = 0; j < 8; ++j) {
            int k = k0 + j;
            v[j] = (_Float16)((row < kO && k < kH) ? fcoW[row * kH + k] : 0.0f);
        }
        *(half8*)((_Float16*)ws + 2LL * FHEAD + (long long)rem * 8) = v;
    }
}

// fused layer-2/3 phase: two matmuls (x-proj + h-proj) + in-register GRU update
__device__ __forceinline__ void layer23(
    const half8* __restrict__ px, const half8* __restrict__ ph,
    const _Float16* __restrict__ fx, const _Float16* __restrict__ fh,
    const float* __restrict__ bsb,       // 4 consecutive [208] arrays: r, z, xn, hn
    float* hreg, _Float16* __restrict__ fbdst, int fboff,
    int j0, int ln) {
    f32x4 ar = {0,0,0,0}, az = {0,0,0,0}, anx = {0,0,0,0}, anh = {0,0,0,0};
    half8 xr = px[0], xz = px[KS * 64], xn = px[2 * KS * 64];
    half8 hr = ph[0], hz = ph[KS * 64], hn = ph[2 * KS * 64];
    #pragma unroll
    for (int ks = 0; ks < KS; ++ks) {
        half8 xr2, xz2, xn2, hr2, hz2, hn2;
        if (ks < KS - 1) {
            xr2 = px[(ks + 1) * 64]; xz2 = px[KS * 64 + (ks + 1) * 64]; xn2 = px[2 * KS * 64 + (ks + 1) * 64];
            hr2 = ph[(ks + 1) * 64]; hz2 = ph[KS * 64 + (ks + 1) * 64]; hn2 = ph[2 * KS * 64 + (ks + 1) * 64];
        }
        half8 bx = *(const half8*)(fx + ((ks * 64 + ln) << 3));
        half8 bh = *(const half8*)(fh + ((ks * 64 + ln) << 3));
        ar  = __builtin_amdgcn_mfma_f32_16x16x32_f16(xr, bx, ar, 0, 0, 0);
        ar  = __builtin_amdgcn_mfma_f32_16x16x32_f16(hr, bh, ar, 0, 0, 0);
        az  = __builtin_amdgcn_mfma_f32_16x16x32_f16(xz, bx, az, 0, 0, 0);
        az  = __builtin_amdgcn_mfma_f32_16x16x32_f16(hz, bh, az, 0, 0, 0);
        anx = __builtin_amdgcn_mfma_f32_16x16x32_f16(xn, bx, anx, 0, 0, 0);
        anh = __builtin_amdgcn_mfma_f32_16x16x32_f16(hn, bh, anh, 0, 0, 0);
        if (ks < KS - 1) { xr = xr2; xz = xz2; xn = xn2; hr = hr2; hz = hz2; hn = hn2; }
    }
    half4_ hv;
    #pragma unroll
    for (int rg = 0; rg < 4; ++rg) {
        int j = j0 + rg;
        float r  = sig_(ar[rg] + bsb[j]);
        float z  = sig_(az[rg] + bsb[208 + j]);
        float nn = tanh_(anx[rg] + bsb[2 * 208 + j] + r * (anh[rg] + bsb[3 * 208 + j]));
        hreg[rg] = (1.0f - z) * nn + z * hreg[rg];
        hv[rg] = (_Float16)hreg[rg];
    }
    *(half4_*)(&fbdst[fboff]) = hv;
}

// head: sigmoid(h3 @ fc_out^T + b) for timestep tt, reading fb3 slice fr
__device__ __forceinline__ void head_mm(
    const half8* __restrict__ WFhd, const _Float16* __restrict__ fr,
    const float* __restrict__ hb, float* __restrict__ out,
    int hw, int tt, int b0, int ln, int lq, int lr) {
    const half8* pw0 = WFhd + hw * (KS * 64) + ln;
    const half8* pw1 = WFhd + 3 * (KS * 64) + ln;   // tile 3, done by hw==0
    f32x4 a0 = {0,0,0,0}, a1 = {0,0,0,0};
    #pragma unroll
    for (int ks = 0; ks < KS; ++ks) {
        half8 bfv = *(const half8*)(fr + ((ks * 64 + ln) << 3));
        a0 = __builtin_amdgcn_mfma_f32_16x16x32_f16(pw0[ks * 64], bfv, a0, 0, 0, 0);
        if (hw == 0) a1 = __builtin_amdgcn_mfma_f32_16x16x32_f16(pw1[ks * 64], bfv, a1, 0, 0, 0);
    }
    int obase = (b0 + lr) * (kT * kO) + tt * kO;
    #pragma unroll
    for (int rg = 0; rg < 4; ++rg) {
        int o = hw * 16 + lq * 4 + rg;
        if (o < kO) out[obase + o] = sig_(a0[rg] + hb[o]);
    }
    if (hw == 0) {
        #pragma unroll
        for (int rg = 0; rg < 4; ++rg) {
            int o = 48 + lq * 4 + rg;
            if (o < kO) out[obase + o] = sig_(a1[rg] + hb[o]);
        }
    }
}

// ---------------- main persistent GRU kernel ----------------
// Validated R6 structure. ONE change: amdgpu_waves_per_eu(4,4) pins occupancy
// at 4 waves/EU (LDS already limits to 1 WG/CU = 4/SIMD) so the register
// allocator uses the full 128-VGPR budget instead of targeting 64 + spilling.
__global__ __launch_bounds__(1024, 4) __attribute__((amdgpu_waves_per_eu(4, 4)))
void gru_main(
    const float* __restrict__ ws,
    const float* __restrict__ h1in, const float* __restrict__ h2in,
    const float* __restrict__ h3in,
    const float* __restrict__ bhh1,
    const float* __restrict__ bih2, const float* __restrict__ bhh2,
    const float* __restrict__ bih3, const float* __restrict__ bhh3,
    const float* __restrict__ fcob,
    float* __restrict__ out) {
    __shared__ float xw1f[3][208 * 17];                 // 42432 B
    __shared__ float bs[9][208];                        // 7488 B
    __shared__ __align__(16) _Float16 fb[3][2][KS * 64 * 8];  // 43008 B
    __shared__ float hb[64];

    const int tid = threadIdx.x, wv = tid >> 6, ln = tid & 63;
    const int lq = ln >> 4, lr = ln & 15;
    const int b0 = blockIdx.x * BT;
    const bool own = (wv < 13);

    // ---- stage xw1 (+ bih1 folded; add bhh1 for r,z) into LDS
    for (int i = tid; i < 3 * 208 * 16; i += 1024) {
        int g = i / (208 * 16), rem = i - g * (208 * 16), j = rem >> 4, n = rem & 15;
        float v = 0.0f;
        if (j < kH) {
            v = ws[XW1 + (b0 + n) * kG + g * kH + j];
            if (g < 2) v += bhh1[g * kH + j];
        }
        xw1f[g][j * 17 + n] = v;
    }
    // ---- biases (208-padded): 0=bhh1_n 1=b2r 2=b2z 3=b2xn 4=b2hn 5=b3r 6=b3z 7=b3xn 8=b3hn
    for (int i = tid; i < 9 * 208; i += 1024) {
        int c = i / 208, j = i - c * 208;
        float v = 0.0f;
        if (j < kH) {
            switch (c) {
                case 0: v = bhh1[2 * kH + j]; break;
                case 1: v = bih2[j] + bhh2[j]; break;
                case 2: v = bih2[kH + j] + bhh2[kH + j]; break;
                case 3: v = bih2[2 * kH + j]; break;
                case 4: v = bhh2[2 * kH + j]; break;
                case 5: v = bih3[j] + bhh3[j]; break;
                case 6: v = bih3[kH + j] + bhh3[kH + j]; break;
                case 7: v = bih3[2 * kH + j]; break;
                default: v = bhh3[2 * kH + j]; break;
            }
        }
        bs[c][j] = v;
    }
    if (tid < 64) hb[tid] = (tid < kO) ? fcob[tid] : 0.0f;

    // ---- zero never-written fb tail (ks=6, lanes 32..63), both parities
    for (int i = tid; i < 3 * 2 * 32 * 8; i += 1024) {
        int l3 = i / 512, rem = i - l3 * 512, par = rem >> 8, r2 = rem & 255;
        fb[l3][par][(6 * 64 + 32 + (r2 >> 3)) * 8 + (r2 & 7)] = (_Float16)0.0f;
    }

    // ---- h states -> registers; parity-0 fb shadows
    float h1r[4], h2r[4], h3r[4];
    const int j0 = wv * 16 + lq * 4;
    int fboff = 0;
    if (own) {
        int ks6 = j0 >> 5, rr = j0 & 31;
        fboff = (((ks6 << 6) + ((rr >> 3) << 4) + lr) << 3) + (rr & 7);
        half4_ v1, v2, v3;
        #pragma unroll
        for (int rg = 0; rg < 4; ++rg) {
            int j = j0 + rg;
            h1r[rg] = (j < kH) ? h1in[(b0 + lr) * kH + j] : 0.0f;
            h2r[rg] = (j < kH) ? h2in[(b0 + lr) * kH + j] : 0.0f;
            h3r[rg] = (j < kH) ? h3in[(b0 + lr) * kH + j] : 0.0f;
            v1[rg] = (_Float16)h1r[rg];
            v2[rg] = (_Float16)h2r[rg];
            v3[rg] = (_Float16)h3r[rg];
        }
        *(half4_*)(&fb[0][0][fboff]) = v1;
        *(half4_*)(&fb[1][0][fboff]) = v2;
        *(half4_*)(&fb[2][0][fboff]) = v3;
    } else {
        #pragma unroll
        for (int rg = 0; rg < 4; ++rg) { h1r[rg] = h2r[rg] = h3r[rg] = 0.0f; }
    }
    __syncthreads();

    const half8* WF1  = (const half8*)(ws + F0);
    const half8* WF2x = (const half8*)(ws + F0 + 1 * FSZ2);
    const half8* WF2h = (const half8*)(ws + F0 + 2 * FSZ2);
    const half8* WF3x = (const half8*)(ws + F0 + 3 * FSZ2);
    const half8* WF3h = (const half8*)(ws + F0 + 4 * FSZ2);
    const half8* WFhd = (const half8*)(ws + FHEAD);
    const int tb = 3 * wv * (KS * 64);   // this wave's r-tile element offset

    for (int t = 0; t < kT; ++t) {
        const int p = t & 1, q = p ^ 1;
        // ---------- phase L1 (waves 0-12)  ||  head(t-1) (waves 13-15) ----------
        if (own) {
            const half8* pw = WF1 + tb + ln;
            const _Float16* fr = fb[0][p];
            f32x4 ra = {0,0,0,0}, za = {0,0,0,0}, na = {0,0,0,0};
            half8 wr = pw[0], wz = pw[KS * 64], wn = pw[2 * KS * 64];
            #pragma unroll
            for (int ks = 0; ks < KS; ++ks) {
                half8 wr2, wz2, wn2;
                if (ks < KS - 1) {
                    wr2 = pw[(ks + 1) * 64];
                    wz2 = pw[KS * 64 + (ks + 1) * 64];
                    wn2 = pw[2 * KS * 64 + (ks + 1) * 64];
                }
                half8 bfv = *(const half8*)(fr + ((ks * 64 + ln) << 3));
                ra = __builtin_amdgcn_mfma_f32_16x16x32_f16(wr, bfv, ra, 0, 0, 0);
                za = __builtin_amdgcn_mfma_f32_16x16x32_f16(wz, bfv, za, 0, 0, 0);
                na = __builtin_amdgcn_mfma_f32_16x16x32_f16(wn, bfv, na, 0, 0, 0);
                if (ks < KS - 1) { wr = wr2; wz = wz2; wn = wn2; }
            }
            half4_ hv;
            #pragma unroll
            for (int rg = 0; rg < 4; ++rg) {
                int j = j0 + rg;
                float r  = sig_(xw1f[0][j * 17 + lr] + ra[rg]);
                float z  = sig_(xw1f[1][j * 17 + lr] + za[rg]);
                float nn = tanh_(xw1f[2][j * 17 + lr] + r * (na[rg] + bs[0][j]));
                h1r[rg] = (1.0f - z) * nn + z * h1r[rg];
                hv[rg] = (_Float16)h1r[rg];
            }
            *(half4_*)(&fb[0][q][fboff]) = hv;
        } else if (t > 0) {
            head_mm(WFhd, fb[2][p], hb, out, wv - 13, t - 1, b0, ln, lq, lr);
        }
        barx();
        // ---------- phase L2 ----------
        if (own) {
            layer23(WF2x + tb + ln, WF2h + tb + ln, fb[0][q], fb[1][p],
                    &bs[1][0], h2r, fb[1][q], fboff, j0, ln);
        }
        barx();
        // ---------- phase L3 ----------
        if (own) {
            layer23(WF3x + tb + ln, WF3h + tb + ln, fb[1][q], fb[2][p],
                    &bs[5][0], h3r, fb[2][q], fboff, j0, ln);
        }
        barx();
    }

    // ---------- final head (t = kT-1) + final h states ----------
    if (!own) {
        head_mm(WFhd, fb[2][kT & 1], hb, out, wv - 13, kT - 1, b0, ln, lq, lr);
    } else {
        #pragma unroll
        for (int rg = 0; rg < 4; ++rg) {
            int j = j0 + rg;
            if (j < kH) {
                out[OH1 + (b0 + lr) * kH + j] = h1r[rg];
                out[OH2 + (b0 + lr) * kH + j] = h2r[rg];
                out[OH3 + (b0 + lr) * kH + j] = h3r[rg];
            }
        }
    }
}

extern "C" void kernel_launch(void* const* d_in, const int* in_sizes, int n_in,
                              void* d_out, int out_size, void* d_ws, size_t ws_size,
                              hipStream_t stream) {
    (void)in_sizes; (void)n_in; (void)out_size; (void)ws_size;
    const float* enc  = (const float*)d_in[0];
    const float* h1in = (const float*)d_in[1];
    const float* h2in = (const float*)d_in[2];
    const float* h3in = (const float*)d_in[3];
    const float* bn_g = (const float*)d_in[4];
    const float* bn_b = (const float*)d_in[5];
    const float* bn_m = (const float*)d_in[6];
    const float* bn_v = (const float*)d_in[7];
    const float* fciW = (const float*)d_in[8];
    const float* fcib = (const float*)d_in[9];
    const float* Wih1 = (const float*)d_in[10];
    const float* Whh1 = (const float*)d_in[11];
    const float* bih1 = (const float*)d_in[12];
    const float* bhh1 = (const float*)d_in[13];
    const float* Wih2 = (const float*)d_in[14];
    const float* Whh2 = (const float*)d_in[15];
    const float* bih2 = (const float*)d_in[16];
    const float* bhh2 = (const float*)d_in[17];
    const float* Wih3 = (const float*)d_in[18];
    const float* Whh3 = (const float*)d_in[19];
    const float* bih3 = (const float*)d_in[20];
    const float* bhh3 = (const float*)d_in[21];
    const float* fcoW = (const float*)d_in[22];
    const float* fcob = (const float*)d_in[23];
    float* ws  = (float*)d_ws;
    float* out = (float*)d_out;

    // order matters: prep_input consumes WIH1T/FCINT before prep_frags overwrites them
    hipLaunchKernelGGL(prep_transpose2, dim3(625), dim3(256), 0, stream, Wih1, fciW, ws);
    hipLaunchKernelGGL(prep_input, dim3(kB), dim3(256), 0, stream,
                       enc, bn_g, bn_b, bn_m, bn_v, fcib, bih1, ws);
    hipLaunchKernelGGL(prep_frags, dim3((5 * PERM2 + 4 * KS * 64 + 255) / 256), dim3(256), 0, stream,
                       Whh1, Wih2, Whh2, Wih3, Whh3, fcoW, ws);
    hipLaunchKernelGGL(gru_main, dim3(NWG), dim3(1024), 0, stream,
                       ws, h1in, h2in, h3in, bhh1, bih2, bhh2, bih3, bhh3, fcob, out);
}

// Round 12
// 1237.023 us; speedup vs baseline: 1.8688x; 1.8688x over previous
//
#include <hip/hip_runtime.h>

typedef _Float16 half8 __attribute__((ext_vector_type(8)));
typedef float f32x4 __attribute__((ext_vector_type(4)));

namespace {
constexpr int kB = 2048;
constexpr int kT = 72;
constexpr int kI = 200;
constexpr int kH = 200;
constexpr int kO = 53;
constexpr int kG = 600;      // 3*kH
constexpr int BT = 8;        // batch rows per WG (8 -> 256 WGs -> all 256 CUs)
constexpr int NWG = kB / BT; // 256
constexpr int MT = 38;       // M tiles of 16 covering 608 (600 padded)
constexpr int KS = 7;        // K slices of 32 covering 224 (200 padded)
constexpr int GSTR = 18;     // LDS G col stride

// ws layout (float offsets) — identical to R4/R9/R10
constexpr int XW1    = 0;          // [2048][600] emb@Wih1^T + bih1
constexpr int WIH1T  = 1228800;    // [200][600] Wih1^T (prep only)
constexpr int FCINT  = 1348800;    // [200][200] fc_in_W^T (prep only)
constexpr int F0     = 1388800;    // fp16 A-frags: hh1, ih2, hh2, ih3, hh3
constexpr int FSZ    = 68096;      // floats per frag matrix
constexpr int FHEAD  = F0 + 5 * FSZ;
constexpr int PERM   = MT * KS * 64;

// output offsets (floats)
constexpr int OH1 = kB * kT * kO;  // 7815168
constexpr int OH2 = OH1 + kB * kH;
constexpr int OH3 = OH2 + kB * kH;
}

__device__ __forceinline__ float sig_(float x) { return 1.0f / (1.0f + __expf(-x)); }
__device__ __forceinline__ float tanh_(float x) {
    return 1.0f - 2.0f / (__expf(2.0f * x) + 1.0f);
}

// barrier draining LDS only; in-flight global weight loads survive (validated R6/R7/R9/R10).
__device__ __forceinline__ void barx() {
    asm volatile("s_waitcnt lgkmcnt(0)\n\ts_barrier" ::: "memory");
}

// fp16 fragment-order shadow write of h element (n, j); n < BT
__device__ __forceinline__ void store_fb(_Float16* fb, int n, int j, float v) {
    int ks = j >> 5, r = j & 31;
    fb[((ks << 6) + ((r >> 3) << 4) + n) * 8 + (r & 7)] = (_Float16)v;
}

// ---------------- prep kernels (identical to R4/R9) ----------------

__global__ __launch_bounds__(256) void prep_transpose2(
    const float* __restrict__ Wih1, const float* __restrict__ fciW,
    float* __restrict__ ws) {
    int idx = blockIdx.x * 256 + threadIdx.x;
    if (idx < 120000) {
        int k = idx / kG, c = idx - k * kG;
        ws[WIH1T + idx] = Wih1[c * kI + k];
    } else {
        int i = idx - 120000;
        if (i < 40000) {
            int k = i / kH, h = i - k * kH;
            ws[FCINT + i] = fciW[h * kI + k];
        }
    }
}

__global__ __launch_bounds__(256) void prep_frags(
    const float* __restrict__ Whh1, const float* __restrict__ Wih2,
    const float* __restrict__ Whh2, const float* __restrict__ Wih3,
    const float* __restrict__ Whh3, const float* __restrict__ fcoW,
    float* __restrict__ ws) {
    int idx = blockIdx.x * 256 + threadIdx.x;
    const float* src; int R; long long dstHalf; int rem;
    if (idx < 5 * PERM) {
        int m = idx / PERM; rem = idx - m * PERM;
        switch (m) {
            case 0: src = Whh1; break;
            case 1: src = Wih2; break;
            case 2: src = Whh2; break;
            case 3: src = Wih3; break;
            default: src = Whh3; break;
        }
        R = kG; dstHalf = 2LL * (F0 + m * FSZ);
    } else {
        rem = idx - 5 * PERM;
        if (rem >= 4 * KS * 64) return;
        src = fcoW; R = kO; dstHalf = 2LL * FHEAD;
    }
    int lane = rem & 63;
    int tmp = rem >> 6;
    int ks = tmp % KS;
    int mt = tmp / KS;
    int row = mt * 16 + (lane & 15);
    int k0 = ks * 32 + (lane >> 4) * 8;
    half8 v;
    #pragma unroll
    for (int j = 0; j < 8; ++j) {
        int k = k0 + j;
        v[j] = (_Float16)((row < R && k < kH) ? src[row * kH + k] : 0.0f);
    }
    *(half8*)((_Float16*)ws + dstHalf + (long long)rem * 8) = v;
}

__global__ __launch_bounds__(256) void prep_input(
    const float* __restrict__ enc,
    const float* __restrict__ bn_g, const float* __restrict__ bn_b,
    const float* __restrict__ bn_m, const float* __restrict__ bn_v,
    const float* __restrict__ fcib, const float* __restrict__ bih1,
    float* ws) {
    __shared__ float xh[kI];
    __shared__ float emb[kH];
    const int b = blockIdx.x, tid = threadIdx.x;
    const float* fcInT = ws + FCINT;
    const float* Wih1T = ws + WIH1T;
    if (tid < kI) {
        float x = enc[b * kI + tid];
        xh[tid] = (x - bn_m[tid]) * rsqrtf(bn_v[tid] + 1e-5f) * bn_g[tid] + bn_b[tid];
    }
    __syncthreads();
    if (tid < kH) {
        float s = fcib[tid];
        for (int k = 0; k < kI; ++k) s = fmaf(xh[k], fcInT[k * kH + tid], s);
        emb[tid] = fmaxf(s, 0.0f);
    }
    __syncthreads();
    for (int c = tid; c < kG; c += 256) {
        float s = bih1[c];
        for (int k = 0; k < kH; ++k) s = fmaf(emb[k], Wih1T[k * kG + c], s);
        ws[XW1 + b * kG + c] = s;
    }
}

// slot load: 6 full ks-slices + exec-masked ks=6 (real k only on lanes 0-15;
// pad lanes get 0, matching the zeroed fb columns -> identical product)
#define LDW(dst, WB, mt) do { \
    const half8* _p = (WB) + ((mt) * KS) * 64 + ln; \
    _Pragma("unroll") \
    for (int _k = 0; _k < KS - 1; ++_k) (dst)[_k] = _p[_k * 64]; \
    if (lo) (dst)[KS - 1] = _p[(KS - 1) * 64]; else (dst)[KS - 1] = z8; \
  } while (0)

// ---------------- main persistent GRU kernel ----------------
// 256 WGs x 512 threads (8 waves, 1 WG/CU). __launch_bounds__(512,1) -> the
// allocator law budget = 512/(2*min) = 256 VGPR (evidence: R7 (512,2)->128,
// R4/R9 (1024,4)->64). Slots (~140 regs) + working set fit 256 without spill.
// R10 schedule: slot prefetch at U-phase tops streams weight VMEM through the
// U phases; 7 lgkm-only barriers/step; pad-trimmed loads everywhere.
__global__ __launch_bounds__(512, 1) void gru_main(
    const float* __restrict__ ws,
    const float* __restrict__ h1in, const float* __restrict__ h2in,
    const float* __restrict__ h3in,
    const float* __restrict__ bhh1,
    const float* __restrict__ bih2, const float* __restrict__ bhh2,
    const float* __restrict__ bih3, const float* __restrict__ bhh3,
    const float* __restrict__ fcob,
    float* __restrict__ out) {
    __shared__ float xwL[kG * BT];                         // 19200 B, [j][n]
    __shared__ __align__(16) _Float16 fb1[KS * 64 * 8];    // 7168 B each
    __shared__ __align__(16) _Float16 fb2[KS * 64 * 8];
    __shared__ __align__(16) _Float16 fb3[KS * 64 * 8];
    __shared__ float Gs[608 * GSTR];                       // 43776 B
    __shared__ float Gns[208 * GSTR];                      // 14976 B
    __shared__ float bias[9 * kH];                         // 7200 B
    __shared__ float hb[64];

    const int tid = threadIdx.x, wv = tid >> 6, ln = tid & 63;
    const int lb = ln >> 4, lr = ln & 15;
    const int b0 = blockIdx.x * BT;
    const bool lo = (ln < 16);
    half8 z8;
    #pragma unroll
    for (int j = 0; j < 8; ++j) z8[j] = (_Float16)0.0f;

    // ---- zero ALL fb slots first (garbage batch-cols 8..15 + K-pad become 0)
    {
        float4* f1 = (float4*)fb1;
        float4* f2 = (float4*)fb2;
        float4* f3 = (float4*)fb3;
        const float4 z4 = {0.f, 0.f, 0.f, 0.f};
        for (int i = tid; i < KS * 64 * 8 * 2 / 16; i += 512) {
            f1[i] = z4; f2[i] = z4; f3[i] = z4;
        }
    }
    // ---- stage xw1 (time-invariant) into LDS, folding bhh1 r/z biases
    for (int i = tid; i < kG * BT; i += 512) {
        int n = i / kG, j = i - n * kG;
        float v = ws[XW1 + (b0 + n) * kG + j];
        if (j < 2 * kH) v += bhh1[j];
        xwL[j * BT + n] = v;
    }
    // ---- biases: [0]=b1n [1]=b2r [2]=b2z [3]=b2xn [4]=b2hn [5..8]=L3
    for (int i = tid; i < 9 * kH; i += 512) {
        int c = i / kH, j = i - c * kH;
        float v;
        switch (c) {
            case 0:  v = bhh1[2 * kH + j]; break;
            case 1:  v = bih2[j] + bhh2[j]; break;
            case 2:  v = bih2[kH + j] + bhh2[kH + j]; break;
            case 3:  v = bih2[2 * kH + j]; break;
            case 4:  v = bhh2[2 * kH + j]; break;
            case 5:  v = bih3[j] + bhh3[j]; break;
            case 6:  v = bih3[kH + j] + bhh3[kH + j]; break;
            case 7:  v = bih3[2 * kH + j]; break;
            default: v = bhh3[2 * kH + j]; break;
        }
        bias[i] = v;
    }
    if (tid < 64) hb[tid] = (tid < kO) ? fcob[tid] : 0.0f;
    __syncthreads();   // fb zeroing complete before shadow writes

    // ---- h states -> registers + fp16 frag shadows (BT*kH = 1600 elems)
    float h1r[4], h2r[4], h3r[4];
    #pragma unroll
    for (int s = 0; s < 4; ++s) {
        int idx = tid + s * 512;
        if (idx < BT * kH) {
            int n = idx & 7, j = idx >> 3;
            h1r[s] = h1in[(b0 + n) * kH + j];
            h2r[s] = h2in[(b0 + n) * kH + j];
            h3r[s] = h3in[(b0 + n) * kH + j];
            store_fb(fb1, n, j, h1r[s]);
            store_fb(fb2, n, j, h2r[s]);
            store_fb(fb3, n, j, h3r[s]);
        } else { h1r[s] = h2r[s] = h3r[s] = 0.0f; }
    }
    __syncthreads();

    const half8* WFhh1 = (const half8*)(ws + F0);
    const half8* WFih2 = (const half8*)(ws + F0 + FSZ);
    const half8* WFhh2 = (const half8*)(ws + F0 + 2 * FSZ);
    const half8* WFih3 = (const half8*)(ws + F0 + 3 * FSZ);
    const half8* WFhh3 = (const half8*)(ws + F0 + 4 * FSZ);
    const half8* WFhead = (const half8*)(ws + FHEAD);

    // ---- prefetch slots
    half8 p1[KS], p2x[KS], p2h[KS], p3x[KS], p3h[KS], whd[KS];
    LDW(p1, WFhh1, wv);
    if (wv < 4) LDW(whd, WFhead, wv);

    for (int t = 0; t < kT; ++t) {
        // ---------- M1: Gs = Whh1 x h1 (slot tile wv; JIT wv+8..) ----------
        {
            half8 bf[KS];
            #pragma unroll
            for (int ks = 0; ks < KS; ++ks)
                bf[ks] = *(const half8*)(fb1 + (ks * 64 + ln) * 8);
            {
                f32x4 acc = {0.f, 0.f, 0.f, 0.f};
                #pragma unroll
                for (int ks = 0; ks < KS; ++ks)
                    acc = __builtin_amdgcn_mfma_f32_16x16x32_f16(p1[ks], bf[ks], acc, 0, 0, 0);
                int row = wv * 16 + lb * 4;
                #pragma unroll
                for (int rg = 0; rg < 4; ++rg) Gs[(row + rg) * GSTR + lr] = acc[rg];
            }
            for (int mt = wv + 8; mt < MT; mt += 8) {
                const half8* wp = WFhh1 + (mt * KS) * 64 + ln;
                half8 w[KS];
                #pragma unroll
                for (int ks = 0; ks < KS - 1; ++ks) w[ks] = wp[ks * 64];
                if (lo) w[KS - 1] = wp[(KS - 1) * 64]; else w[KS - 1] = z8;
                f32x4 acc = {0.f, 0.f, 0.f, 0.f};
                #pragma unroll
                for (int ks = 0; ks < KS; ++ks)
                    acc = __builtin_amdgcn_mfma_f32_16x16x32_f16(w[ks], bf[ks], acc, 0, 0, 0);
                int row = mt * 16 + lb * 4;
                #pragma unroll
                for (int rg = 0; rg < 4; ++rg) Gs[(row + rg) * GSTR + lr] = acc[rg];
            }
        }
        barx();
        // ---------- U1: update h1 (M2 slot loads stream underneath) ----------
        LDW(p2x, WFih2, wv);
        LDW(p2h, WFhh2, wv);
        #pragma unroll
        for (int s = 0; s < 4; ++s) {
            int idx = tid + s * 512;
            if (idx < BT * kH) {
                int n = idx & 7, j = idx >> 3;
                float r  = sig_(xwL[j * BT + n]            + Gs[j * GSTR + n]);
                float z  = sig_(xwL[(kH + j) * BT + n]     + Gs[(kH + j) * GSTR + n]);
                float nn = tanh_(xwL[(2 * kH + j) * BT + n] + r * (Gs[(2 * kH + j) * GSTR + n] + bias[j]));
                h1r[s] = (1.0f - z) * nn + z * h1r[s];
                store_fb(fb1, n, j, h1r[s]);
            }
        }
        barx();
        // ---------- M2: Wih2 x h1 + Whh2 x h2 (slot wv; JIT rest) ----------
        {
            half8 bx[KS], bh[KS];
            #pragma unroll
            for (int ks = 0; ks < KS; ++ks) {
                bx[ks] = *(const half8*)(fb1 + (ks * 64 + ln) * 8);
                bh[ks] = *(const half8*)(fb2 + (ks * 64 + ln) * 8);
            }
            {
                f32x4 ax = {0.f, 0.f, 0.f, 0.f}, ah = {0.f, 0.f, 0.f, 0.f};
                #pragma unroll
                for (int ks = 0; ks < KS; ++ks) {
                    ax = __builtin_amdgcn_mfma_f32_16x16x32_f16(p2x[ks], bx[ks], ax, 0, 0, 0);
                    ah = __builtin_amdgcn_mfma_f32_16x16x32_f16(p2h[ks], bh[ks], ah, 0, 0, 0);
                }
                int row = wv * 16 + lb * 4;  // wv < 8 -> combined store region
                #pragma unroll
                for (int rg = 0; rg < 4; ++rg) Gs[(row + rg) * GSTR + lr] = ax[rg] + ah[rg];
            }
            for (int mt = wv + 8; mt < MT; mt += 8) {
                const half8* wpx = WFih2 + (mt * KS) * 64 + ln;
                const half8* wph = WFhh2 + (mt * KS) * 64 + ln;
                half8 wx[KS], wh[KS];
                #pragma unroll
                for (int ks = 0; ks < KS - 1; ++ks) { wx[ks] = wpx[ks * 64]; wh[ks] = wph[ks * 64]; }
                if (lo) { wx[KS - 1] = wpx[(KS - 1) * 64]; wh[KS - 1] = wph[(KS - 1) * 64]; }
                else    { wx[KS - 1] = z8; wh[KS - 1] = z8; }
                f32x4 ax = {0.f, 0.f, 0.f, 0.f}, ah = {0.f, 0.f, 0.f, 0.f};
                #pragma unroll
                for (int ks = 0; ks < KS; ++ks) {
                    ax = __builtin_amdgcn_mfma_f32_16x16x32_f16(wx[ks], bx[ks], ax, 0, 0, 0);
                    ah = __builtin_amdgcn_mfma_f32_16x16x32_f16(wh[ks], bh[ks], ah, 0, 0, 0);
                }
                int row = mt * 16 + lb * 4;
                if (mt < 25) {
                    #pragma unroll
                    for (int rg = 0; rg < 4; ++rg) Gs[(row + rg) * GSTR + lr] = ax[rg] + ah[rg];
                } else {
                    #pragma unroll
                    for (int rg = 0; rg < 4; ++rg) {
                        Gs[(row + rg) * GSTR + lr] = ax[rg];
                        Gns[(row - 400 + rg) * GSTR + lr] = ah[rg];
                    }
                }
            }
        }
        barx();
        // ---------- U2: update h2 (M3 slot loads stream underneath) ----------
        LDW(p3x, WFih3, wv);
        LDW(p3h, WFhh3, wv);
        #pragma unroll
        for (int s = 0; s < 4; ++s) {
            int idx = tid + s * 512;
            if (idx < BT * kH) {
                int n = idx & 7, j = idx >> 3;
                float r  = sig_(Gs[j * GSTR + n]            + bias[kH + j]);
                float z  = sig_(Gs[(kH + j) * GSTR + n]     + bias[2 * kH + j]);
                float nn = tanh_(Gs[(2 * kH + j) * GSTR + n] + bias[3 * kH + j]
                                 + r * (Gns[j * GSTR + n]   + bias[4 * kH + j]));
                h2r[s] = (1.0f - z) * nn + z * h2r[s];
                store_fb(fb2, n, j, h2r[s]);
            }
        }
        barx();
        // ---------- M3: Wih3 x h2 + Whh3 x h3 (slot wv; JIT rest) ----------
        {
            half8 bx[KS], bh[KS];
            #pragma unroll
            for (int ks = 0; ks < KS; ++ks) {
                bx[ks] = *(const half8*)(fb2 + (ks * 64 + ln) * 8);
                bh[ks] = *(const half8*)(fb3 + (ks * 64 + ln) * 8);
            }
            {
                f32x4 ax = {0.f, 0.f, 0.f, 0.f}, ah = {0.f, 0.f, 0.f, 0.f};
                #pragma unroll
                for (int ks = 0; ks < KS; ++ks) {
                    ax = __builtin_amdgcn_mfma_f32_16x16x32_f16(p3x[ks], bx[ks], ax, 0, 0, 0);
                    ah = __builtin_amdgcn_mfma_f32_16x16x32_f16(p3h[ks], bh[ks], ah, 0, 0, 0);
                }
                int row = wv * 16 + lb * 4;
                #pragma unroll
                for (int rg = 0; rg < 4; ++rg) Gs[(row + rg) * GSTR + lr] = ax[rg] + ah[rg];
            }
            for (int mt = wv + 8; mt < MT; mt += 8) {
                const half8* wpx = WFih3 + (mt * KS) * 64 + ln;
                const half8* wph = WFhh3 + (mt * KS) * 64 + ln;
                half8 wx[KS], wh[KS];
                #pragma unroll
                for (int ks = 0; ks < KS - 1; ++ks) { wx[ks] = wpx[ks * 64]; wh[ks] = wph[ks * 64]; }
                if (lo) { wx[KS - 1] = wpx[(KS - 1) * 64]; wh[KS - 1] = wph[(KS - 1) * 64]; }
                else    { wx[KS - 1] = z8; wh[KS - 1] = z8; }
                f32x4 ax = {0.f, 0.f, 0.f, 0.f}, ah = {0.f, 0.f, 0.f, 0.f};
                #pragma unroll
                for (int ks = 0; ks < KS; ++ks) {
                    ax = __builtin_amdgcn_mfma_f32_16x16x32_f16(wx[ks], bx[ks], ax, 0, 0, 0);
                    ah = __builtin_amdgcn_mfma_f32_16x16x32_f16(wh[ks], bh[ks], ah, 0, 0, 0);
                }
                int row = mt * 16 + lb * 4;
                if (mt < 25) {
                    #pragma unroll
                    for (int rg = 0; rg < 4; ++rg) Gs[(row + rg) * GSTR + lr] = ax[rg] + ah[rg];
                } else {
                    #pragma unroll
                    for (int rg = 0; rg < 4; ++rg) {
                        Gs[(row + rg) * GSTR + lr] = ax[rg];
                        Gns[(row - 400 + rg) * GSTR + lr] = ah[rg];
                    }
                }
            }
        }
        barx();
        // ---------- U3: update h3 (next-step M1 slot loads stream underneath) ----------
        LDW(p1, WFhh1, wv);
        #pragma unroll
        for (int s = 0; s < 4; ++s) {
            int idx = tid + s * 512;
            if (idx < BT * kH) {
                int n = idx & 7, j = idx >> 3;
                float r  = sig_(Gs[j * GSTR + n]            + bias[5 * kH + j]);
                float z  = sig_(Gs[(kH + j) * GSTR + n]     + bias[6 * kH + j]);
                float nn = tanh_(Gs[(2 * kH + j) * GSTR + n] + bias[7 * kH + j]
                                 + r * (Gns[j * GSTR + n]   + bias[8 * kH + j]));
                h3r[s] = (1.0f - z) * nn + z * h3r[s];
                store_fb(fb3, n, j, h3r[s]);
            }
        }
        barx();
        // ---------- HEAD (waves 0..3, wave-uniform MFMA; stores guarded) ----------
        if (wv < 4) {
            half8 bf[KS];
            #pragma unroll
            for (int ks = 0; ks < KS; ++ks)
                bf[ks] = *(const half8*)(fb3 + (ks * 64 + ln) * 8);
            f32x4 acc = {0.f, 0.f, 0.f, 0.f};
            #pragma unroll
            for (int ks = 0; ks < KS; ++ks)
                acc = __builtin_amdgcn_mfma_f32_16x16x32_f16(whd[ks], bf[ks], acc, 0, 0, 0);
            if (lr < BT) {
                int o0 = wv * 16 + lb * 4;
                int obase = (b0 + lr) * (kT * kO) + t * kO;
                #pragma unroll
                for (int rg = 0; rg < 4; ++rg) {
                    int o = o0 + rg;
                    if (o < kO) out[obase + o] = sig_(acc[rg] + hb[o]);
                }
            }
        }
        barx();
    }

    // ---- final hidden states: stage in LDS (Gs) for coalesced global writes
    #pragma unroll
    for (int s = 0; s < 4; ++s) {
        int idx = tid + s * 512;
        if (idx < BT * kH) {
            Gs[idx] = h1r[s];
            Gs[1600 + idx] = h2r[s];
            Gs[3200 + idx] = h3r[s];
        }
    }
    __syncthreads();
    for (int i = tid; i < BT * kH; i += 512) {
        int n = i / kH, j = i - n * kH;
        int src = j * BT + n;
        out[OH1 + (b0 + n) * kH + j] = Gs[src];
        out[OH2 + (b0 + n) * kH + j] = Gs[1600 + src];
        out[OH3 + (b0 + n) * kH + j] = Gs[3200 + src];
    }
}

extern "C" void kernel_launch(void* const* d_in, const int* in_sizes, int n_in,
                              void* d_out, int out_size, void* d_ws, size_t ws_size,
                              hipStream_t stream) {
    (void)in_sizes; (void)n_in; (void)out_size; (void)ws_size;
    const float* enc  = (const float*)d_in[0];
    const float* h1in = (const float*)d_in[1];
    const float* h2in = (const float*)d_in[2];
    const float* h3in = (const float*)d_in[3];
    const float* bn_g = (const float*)d_in[4];
    const float* bn_b = (const float*)d_in[5];
    const float* bn_m = (const float*)d_in[6];
    const float* bn_v = (const float*)d_in[7];
    const float* fciW = (const float*)d_in[8];
    const float* fcib = (const float*)d_in[9];
    const float* Wih1 = (const float*)d_in[10];
    const float* Whh1 = (const float*)d_in[11];
    const float* bih1 = (const float*)d_in[12];
    const float* bhh1 = (const float*)d_in[13];
    const float* Wih2 = (const float*)d_in[14];
    const float* Whh2 = (const float*)d_in[15];
    const float* bih2 = (const float*)d_in[16];
    const float* bhh2 = (const float*)d_in[17];
    const float* Wih3 = (const float*)d_in[18];
    const float* Whh3 = (const float*)d_in[19];
    const float* bih3 = (const float*)d_in[20];
    const float* bhh3 = (const float*)d_in[21];
    const float* fcoW = (const float*)d_in[22];
    const float* fcob = (const float*)d_in[23];
    float* ws  = (float*)d_ws;
    float* out = (float*)d_out;

    hipLaunchKernelGGL(prep_transpose2, dim3(625), dim3(256), 0, stream, Wih1, fciW, ws);
    hipLaunchKernelGGL(prep_frags, dim3(340), dim3(256), 0, stream,
                       Whh1, Wih2, Whh2, Wih3, Whh3, fcoW, ws);
    hipLaunchKernelGGL(prep_input, dim3(kB), dim3(256), 0, stream,
                       enc, bn_g, bn_b, bn_m, bn_v, fcib, bih1, ws);
    hipLaunchKernelGGL(gru_main, dim3(NWG), dim3(512), 0, stream,
                       ws, h1in, h2in, h3in, bhh1, bih2, bhh2, bih3, bhh3, fcob, out);
}

// Round 13
// 1110.548 us; speedup vs baseline: 2.0816x; 1.1139x over previous
//
#include <hip/hip_runtime.h>

typedef _Float16 half8 __attribute__((ext_vector_type(8)));
typedef float f32x4 __attribute__((ext_vector_type(4)));

namespace {
constexpr int kB = 2048;
constexpr int kT = 72;
constexpr int kI = 200;
constexpr int kH = 200;
constexpr int kO = 53;
constexpr int kG = 600;      // 3*kH
constexpr int BT = 8;        // batch rows per WG (8 -> 256 WGs -> all 256 CUs)
constexpr int NWG = kB / BT; // 256
constexpr int MT = 38;       // M tiles of 16 covering 608 (600 padded)
constexpr int KS = 7;        // K slices of 32 covering 224 (200 padded)
constexpr int GSTR = 18;     // LDS G col stride

// ws layout (float offsets) — identical to R4/R9
constexpr int XW1    = 0;          // [2048][600] emb@Wih1^T + bih1
constexpr int WIH1T  = 1228800;    // [200][600] Wih1^T (prep only)
constexpr int FCINT  = 1348800;    // [200][200] fc_in_W^T (prep only)
constexpr int F0     = 1388800;    // fp16 A-frags: hh1, ih2, hh2, ih3, hh3
constexpr int FSZ    = 68096;      // floats per frag matrix
constexpr int FHEAD  = F0 + 5 * FSZ;
constexpr int PERM   = MT * KS * 64;

// output offsets (floats)
constexpr int OH1 = kB * kT * kO;  // 7815168
constexpr int OH2 = OH1 + kB * kH;
constexpr int OH3 = OH2 + kB * kH;
}

__device__ __forceinline__ float sig_(float x) { return 1.0f / (1.0f + __expf(-x)); }
__device__ __forceinline__ float tanh_(float x) {
    return 1.0f - 2.0f / (__expf(2.0f * x) + 1.0f);
}

// barrier draining LDS only; in-flight global weight loads survive (validated R6/R7/R9/R12).
__device__ __forceinline__ void barx() {
    asm volatile("s_waitcnt lgkmcnt(0)\n\ts_barrier" ::: "memory");
}

// fp16 fragment-order shadow write of h element (n, j); n < BT
__device__ __forceinline__ void store_fb(_Float16* fb, int n, int j, float v) {
    int ks = j >> 5, r = j & 31;
    fb[((ks << 6) + ((r >> 3) << 4) + n) * 8 + (r & 7)] = (_Float16)v;
}

// ---------------- prep kernels (identical to R4/R9) ----------------

__global__ __launch_bounds__(256) void prep_transpose2(
    const float* __restrict__ Wih1, const float* __restrict__ fciW,
    float* __restrict__ ws) {
    int idx = blockIdx.x * 256 + threadIdx.x;
    if (idx < 120000) {
        int k = idx / kG, c = idx - k * kG;
        ws[WIH1T + idx] = Wih1[c * kI + k];
    } else {
        int i = idx - 120000;
        if (i < 40000) {
            int k = i / kH, h = i - k * kH;
            ws[FCINT + i] = fciW[h * kI + k];
        }
    }
}

__global__ __launch_bounds__(256) void prep_frags(
    const float* __restrict__ Whh1, const float* __restrict__ Wih2,
    const float* __restrict__ Whh2, const float* __restrict__ Wih3,
    const float* __restrict__ Whh3, const float* __restrict__ fcoW,
    float* __restrict__ ws) {
    int idx = blockIdx.x * 256 + threadIdx.x;
    const float* src; int R; long long dstHalf; int rem;
    if (idx < 5 * PERM) {
        int m = idx / PERM; rem = idx - m * PERM;
        switch (m) {
            case 0: src = Whh1; break;
            case 1: src = Wih2; break;
            case 2: src = Whh2; break;
            case 3: src = Wih3; break;
            default: src = Whh3; break;
        }
        R = kG; dstHalf = 2LL * (F0 + m * FSZ);
    } else {
        rem = idx - 5 * PERM;
        if (rem >= 4 * KS * 64) return;
        src = fcoW; R = kO; dstHalf = 2LL * FHEAD;
    }
    int lane = rem & 63;
    int tmp = rem >> 6;
    int ks = tmp % KS;
    int mt = tmp / KS;
    int row = mt * 16 + (lane & 15);
    int k0 = ks * 32 + (lane >> 4) * 8;
    half8 v;
    #pragma unroll
    for (int j = 0; j < 8; ++j) {
        int k = k0 + j;
        v[j] = (_Float16)((row < R && k < kH) ? src[row * kH + k] : 0.0f);
    }
    *(half8*)((_Float16*)ws + dstHalf + (long long)rem * 8) = v;
}

__global__ __launch_bounds__(256) void prep_input(
    const float* __restrict__ enc,
    const float* __restrict__ bn_g, const float* __restrict__ bn_b,
    const float* __restrict__ bn_m, const float* __restrict__ bn_v,
    const float* __restrict__ fcib, const float* __restrict__ bih1,
    float* ws) {
    __shared__ float xh[kI];
    __shared__ float emb[kH];
    const int b = blockIdx.x, tid = threadIdx.x;
    const float* fcInT = ws + FCINT;
    const float* Wih1T = ws + WIH1T;
    if (tid < kI) {
        float x = enc[b * kI + tid];
        xh[tid] = (x - bn_m[tid]) * rsqrtf(bn_v[tid] + 1e-5f) * bn_g[tid] + bn_b[tid];
    }
    __syncthreads();
    if (tid < kH) {
        float s = fcib[tid];
        for (int k = 0; k < kI; ++k) s = fmaf(xh[k], fcInT[k * kH + tid], s);
        emb[tid] = fmaxf(s, 0.0f);
    }
    __syncthreads();
    for (int c = tid; c < kG; c += 256) {
        float s = bih1[c];
        for (int k = 0; k < kH; ++k) s = fmaf(emb[k], Wih1T[k * kG + c], s);
        ws[XW1 + b * kG + c] = s;
    }
}

// ---------------- main persistent GRU kernel ----------------
// 256 WGs x 1024 threads (16 waves), one per CU. WG owns 8 batch rows.
// R9 skeleton exactly (validated, 1150 us) + two bit-exact byte cuts:
//  (a) ks=6 pad trim: packed frags for k>=200 are zeros by construction;
//      load only lanes 0-15 (k=192..199), substitute z8 elsewhere.
//  (b) head weights staged in LDS once at init (28.7 KB), removing a
//      28.7 KB/step re-load of time-invariant data.
__global__ __launch_bounds__(1024, 4) void gru_main(
    const float* __restrict__ ws,
    const float* __restrict__ h1in, const float* __restrict__ h2in,
    const float* __restrict__ h3in,
    const float* __restrict__ bhh1,
    const float* __restrict__ bih2, const float* __restrict__ bhh2,
    const float* __restrict__ bih3, const float* __restrict__ bhh3,
    const float* __restrict__ fcob,
    float* __restrict__ out) {
    __shared__ float xwL[kG * BT];                         // 19200 B, [j][n]
    __shared__ __align__(16) _Float16 fb1[KS * 64 * 8];    // 7168 B each
    __shared__ __align__(16) _Float16 fb2[KS * 64 * 8];
    __shared__ __align__(16) _Float16 fb3[KS * 64 * 8];
    __shared__ __align__(16) _Float16 whdL[4 * KS * 64 * 8]; // 28672 B head frags
    __shared__ float Gs[608 * GSTR];                       // 43776 B
    __shared__ float Gns[208 * GSTR];                      // 14976 B
    __shared__ float bias[9 * kH];                         // 7200 B
    __shared__ float hb[64];

    const int tid = threadIdx.x, wv = tid >> 6, ln = tid & 63;
    const int lb = ln >> 4, lr = ln & 15;
    const int b0 = blockIdx.x * BT;
    const bool lo = (ln < 16);
    half8 z8;
    #pragma unroll
    for (int j = 0; j < 8; ++j) z8[j] = (_Float16)0.0f;

    // ---- zero ALL fb slots first (garbage batch-cols 8..15 + K-pad become 0)
    {
        float4* f1 = (float4*)fb1;
        float4* f2 = (float4*)fb2;
        float4* f3 = (float4*)fb3;
        const float4 z4 = {0.f, 0.f, 0.f, 0.f};
        for (int i = tid; i < KS * 64 * 8 * 2 / 16; i += 1024) {
            f1[i] = z4; f2[i] = z4; f3[i] = z4;
        }
    }
    // ---- head weights -> LDS (time-invariant, read every step)
    {
        const half8* src = (const half8*)(ws + FHEAD);
        for (int i = tid; i < 4 * KS * 64; i += 1024)
            *(half8*)(whdL + (long long)i * 8) = src[i];
    }
    // ---- stage xw1 (time-invariant) into LDS, folding bhh1 r/z biases
    for (int i = tid; i < kG * BT; i += 1024) {
        int n = i / kG, j = i - n * kG;
        float v = ws[XW1 + (b0 + n) * kG + j];
        if (j < 2 * kH) v += bhh1[j];
        xwL[j * BT + n] = v;
    }
    // ---- biases: [0]=b1n [1]=b2r [2]=b2z [3]=b2xn [4]=b2hn [5..8]=L3
    for (int i = tid; i < 9 * kH; i += 1024) {
        int c = i / kH, j = i - c * kH;
        float v;
        switch (c) {
            case 0:  v = bhh1[2 * kH + j]; break;
            case 1:  v = bih2[j] + bhh2[j]; break;
            case 2:  v = bih2[kH + j] + bhh2[kH + j]; break;
            case 3:  v = bih2[2 * kH + j]; break;
            case 4:  v = bhh2[2 * kH + j]; break;
            case 5:  v = bih3[j] + bhh3[j]; break;
            case 6:  v = bih3[kH + j] + bhh3[kH + j]; break;
            case 7:  v = bih3[2 * kH + j]; break;
            default: v = bhh3[2 * kH + j]; break;
        }
        bias[i] = v;
    }
    if (tid < 64) hb[tid] = (tid < kO) ? fcob[tid] : 0.0f;
    __syncthreads();   // fb zeroing complete before shadow writes

    // ---- h states -> registers + fp16 frag shadows (BT*kH = 1600 elems)
    float h1r[2], h2r[2], h3r[2];
    #pragma unroll
    for (int s = 0; s < 2; ++s) {
        int idx = tid + s * 1024;
        if (idx < BT * kH) {
            int n = idx & 7, j = idx >> 3;
            h1r[s] = h1in[(b0 + n) * kH + j];
            h2r[s] = h2in[(b0 + n) * kH + j];
            h3r[s] = h3in[(b0 + n) * kH + j];
            store_fb(fb1, n, j, h1r[s]);
            store_fb(fb2, n, j, h2r[s]);
            store_fb(fb3, n, j, h3r[s]);
        } else { h1r[s] = h2r[s] = h3r[s] = 0.0f; }
    }
    __syncthreads();

    const half8* WFhh1 = (const half8*)(ws + F0);
    const half8* WFih2 = (const half8*)(ws + F0 + FSZ);
    const half8* WFhh2 = (const half8*)(ws + F0 + 2 * FSZ);
    const half8* WFih3 = (const half8*)(ws + F0 + 3 * FSZ);
    const half8* WFhh3 = (const half8*)(ws + F0 + 4 * FSZ);

    for (int t = 0; t < kT; ++t) {
        // ---------- M1: Gs = Whh1 x h1 ----------
        {
            half8 bf[KS];
            #pragma unroll
            for (int ks = 0; ks < KS; ++ks)
                bf[ks] = *(const half8*)(fb1 + (ks * 64 + ln) * 8);
            for (int mt = wv; mt < MT; mt += 16) {
                const half8* wp = WFhh1 + (mt * KS) * 64 + ln;
                f32x4 acc = {0.f, 0.f, 0.f, 0.f};
                #pragma unroll
                for (int ks = 0; ks < KS - 1; ++ks)
                    acc = __builtin_amdgcn_mfma_f32_16x16x32_f16(wp[ks * 64], bf[ks], acc, 0, 0, 0);
                half8 w6 = z8;
                if (lo) w6 = wp[(KS - 1) * 64];
                acc = __builtin_amdgcn_mfma_f32_16x16x32_f16(w6, bf[KS - 1], acc, 0, 0, 0);
                int row = mt * 16 + lb * 4;
                #pragma unroll
                for (int rg = 0; rg < 4; ++rg) Gs[(row + rg) * GSTR + lr] = acc[rg];
            }
        }
        barx();
        // ---------- U1: update h1 ----------
        #pragma unroll
        for (int s = 0; s < 2; ++s) {
            int idx = tid + s * 1024;
            if (idx < BT * kH) {
                int n = idx & 7, j = idx >> 3;
                float r  = sig_(xwL[j * BT + n]            + Gs[j * GSTR + n]);
                float z  = sig_(xwL[(kH + j) * BT + n]     + Gs[(kH + j) * GSTR + n]);
                float nn = tanh_(xwL[(2 * kH + j) * BT + n] + r * (Gs[(2 * kH + j) * GSTR + n] + bias[j]));
                h1r[s] = (1.0f - z) * nn + z * h1r[s];
                store_fb(fb1, n, j, h1r[s]);
            }
        }
        barx();
        // ---------- M2: Wih2 x h1 + Whh2 x h2 ----------
        {
            half8 bx[KS], bh[KS];
            #pragma unroll
            for (int ks = 0; ks < KS; ++ks) {
                bx[ks] = *(const half8*)(fb1 + (ks * 64 + ln) * 8);
                bh[ks] = *(const half8*)(fb2 + (ks * 64 + ln) * 8);
            }
            for (int mt = wv; mt < MT; mt += 16) {
                const half8* wpx = WFih2 + (mt * KS) * 64 + ln;
                const half8* wph = WFhh2 + (mt * KS) * 64 + ln;
                f32x4 ax = {0.f, 0.f, 0.f, 0.f}, ah = {0.f, 0.f, 0.f, 0.f};
                #pragma unroll
                for (int ks = 0; ks < KS - 1; ++ks) {
                    ax = __builtin_amdgcn_mfma_f32_16x16x32_f16(wpx[ks * 64], bx[ks], ax, 0, 0, 0);
                    ah = __builtin_amdgcn_mfma_f32_16x16x32_f16(wph[ks * 64], bh[ks], ah, 0, 0, 0);
                }
                half8 wx6 = z8, wh6 = z8;
                if (lo) { wx6 = wpx[(KS - 1) * 64]; wh6 = wph[(KS - 1) * 64]; }
                ax = __builtin_amdgcn_mfma_f32_16x16x32_f16(wx6, bx[KS - 1], ax, 0, 0, 0);
                ah = __builtin_amdgcn_mfma_f32_16x16x32_f16(wh6, bh[KS - 1], ah, 0, 0, 0);
                int row = mt * 16 + lb * 4;
                if (mt < 25) {
                    #pragma unroll
                    for (int rg = 0; rg < 4; ++rg) Gs[(row + rg) * GSTR + lr] = ax[rg] + ah[rg];
                } else {
                    #pragma unroll
                    for (int rg = 0; rg < 4; ++rg) {
                        Gs[(row + rg) * GSTR + lr] = ax[rg];
                        Gns[(row - 400 + rg) * GSTR + lr] = ah[rg];
                    }
                }
            }
        }
        barx();
        // ---------- U2: update h2 ----------
        #pragma unroll
        for (int s = 0; s < 2; ++s) {
            int idx = tid + s * 1024;
            if (idx < BT * kH) {
                int n = idx & 7, j = idx >> 3;
                float r  = sig_(Gs[j * GSTR + n]            + bias[kH + j]);
                float z  = sig_(Gs[(kH + j) * GSTR + n]     + bias[2 * kH + j]);
                float nn = tanh_(Gs[(2 * kH + j) * GSTR + n] + bias[3 * kH + j]
                                 + r * (Gns[j * GSTR + n]   + bias[4 * kH + j]));
                h2r[s] = (1.0f - z) * nn + z * h2r[s];
                store_fb(fb2, n, j, h2r[s]);
            }
        }
        barx();
        // ---------- M3: Wih3 x h2 + Whh3 x h3 ----------
        {
            half8 bx[KS], bh[KS];
            #pragma unroll
            for (int ks = 0; ks < KS; ++ks) {
                bx[ks] = *(const half8*)(fb2 + (ks * 64 + ln) * 8);
                bh[ks] = *(const half8*)(fb3 + (ks * 64 + ln) * 8);
            }
            for (int mt = wv; mt < MT; mt += 16) {
                const half8* wpx = WFih3 + (mt * KS) * 64 + ln;
                const half8* wph = WFhh3 + (mt * KS) * 64 + ln;
                f32x4 ax = {0.f, 0.f, 0.f, 0.f}, ah = {0.f, 0.f, 0.f, 0.f};
                #pragma unroll
                for (int ks = 0; ks < KS - 1; ++ks) {
                    ax = __builtin_amdgcn_mfma_f32_16x16x32_f16(wpx[ks * 64], bx[ks], ax, 0, 0, 0);
                    ah = __builtin_amdgcn_mfma_f32_16x16x32_f16(wph[ks * 64], bh[ks], ah, 0, 0, 0);
                }
                half8 wx6 = z8, wh6 = z8;
                if (lo) { wx6 = wpx[(KS - 1) * 64]; wh6 = wph[(KS - 1) * 64]; }
                ax = __builtin_amdgcn_mfma_f32_16x16x32_f16(wx6, bx[KS - 1], ax, 0, 0, 0);
                ah = __builtin_amdgcn_mfma_f32_16x16x32_f16(wh6, bh[KS - 1], ah, 0, 0, 0);
                int row = mt * 16 + lb * 4;
                if (mt < 25) {
                    #pragma unroll
                    for (int rg = 0; rg < 4; ++rg) Gs[(row + rg) * GSTR + lr] = ax[rg] + ah[rg];
                } else {
                    #pragma unroll
                    for (int rg = 0; rg < 4; ++rg) {
                        Gs[(row + rg) * GSTR + lr] = ax[rg];
                        Gns[(row - 400 + rg) * GSTR + lr] = ah[rg];
                    }
                }
            }
        }
        barx();
        // ---------- U3: update h3 ----------
        #pragma unroll
        for (int s = 0; s < 2; ++s) {
            int idx = tid + s * 1024;
            if (idx < BT * kH) {
                int n = idx & 7, j = idx >> 3;
                float r  = sig_(Gs[j * GSTR + n]            + bias[5 * kH + j]);
                float z  = sig_(Gs[(kH + j) * GSTR + n]     + bias[6 * kH + j]);
                float nn = tanh_(Gs[(2 * kH + j) * GSTR + n] + bias[7 * kH + j]
                                 + r * (Gns[j * GSTR + n]   + bias[8 * kH + j]));
                h3r[s] = (1.0f - z) * nn + z * h3r[s];
                store_fb(fb3, n, j, h3r[s]);
            }
        }
        barx();
        // ---------- HEAD (waves 0..3, wave-uniform MFMA from LDS; stores guarded) ----------
        if (wv < 4) {
            f32x4 acc = {0.f, 0.f, 0.f, 0.f};
            #pragma unroll
            for (int ks = 0; ks < KS; ++ks) {
                half8 w = *(const half8*)(whdL + ((wv * KS + ks) * 64 + ln) * 8);
                half8 b = *(const half8*)(fb3 + (ks * 64 + ln) * 8);
                acc = __builtin_amdgcn_mfma_f32_16x16x32_f16(w, b, acc, 0, 0, 0);
            }
            if (lr < BT) {
                int o0 = wv * 16 + lb * 4;
                int obase = (b0 + lr) * (kT * kO) + t * kO;
                #pragma unroll
                for (int rg = 0; rg < 4; ++rg) {
                    int o = o0 + rg;
                    if (o < kO) out[obase + o] = sig_(acc[rg] + hb[o]);
                }
            }
        }
        barx();
    }

    // ---- final hidden states: stage in LDS (Gs) for coalesced global writes
    #pragma unroll
    for (int s = 0; s < 2; ++s) {
        int idx = tid + s * 1024;
        if (idx < BT * kH) {
            Gs[idx] = h1r[s];
            Gs[1600 + idx] = h2r[s];
            Gs[3200 + idx] = h3r[s];
        }
    }
    __syncthreads();
    for (int i = tid; i < BT * kH; i += 1024) {
        int n = i / kH, j = i - n * kH;
        int src = j * BT + n;
        out[OH1 + (b0 + n) * kH + j] = Gs[src];
        out[OH2 + (b0 + n) * kH + j] = Gs[1600 + src];
        out[OH3 + (b0 + n) * kH + j] = Gs[3200 + src];
    }
}

extern "C" void kernel_launch(void* const* d_in, const int* in_sizes, int n_in,
                              void* d_out, int out_size, void* d_ws, size_t ws_size,
                              hipStream_t stream) {
    (void)in_sizes; (void)n_in; (void)out_size; (void)ws_size;
    const float* enc  = (const float*)d_in[0];
    const float* h1in = (const float*)d_in[1];
    const float* h2in = (const float*)d_in[2];
    const float* h3in = (const float*)d_in[3];
    const float* bn_g = (const float*)d_in[4];
    const float* bn_b = (const float*)d_in[5];
    const float* bn_m = (const float*)d_in[6];
    const float* bn_v = (const float*)d_in[7];
    const float* fciW = (const float*)d_in[8];
    const float* fcib = (const float*)d_in[9];
    const float* Wih1 = (const float*)d_in[10];
    const float* Whh1 = (const float*)d_in[11];
    const float* bih1 = (const float*)d_in[12];
    const float* bhh1 = (const float*)d_in[13];
    const float* Wih2 = (const float*)d_in[14];
    const float* Whh2 = (const float*)d_in[15];
    const float* bih2 = (const float*)d_in[16];
    const float* bhh2 = (const float*)d_in[17];
    const float* Wih3 = (const float*)d_in[18];
    const float* Whh3 = (const float*)d_in[19];
    const float* bih3 = (const float*)d_in[20];
    const float* bhh3 = (const float*)d_in[21];
    const float* fcoW = (const float*)d_in[22];
    const float* fcob = (const float*)d_in[23];
    float* ws  = (float*)d_ws;
    float* out = (float*)d_out;

    hipLaunchKernelGGL(prep_transpose2, dim3(625), dim3(256), 0, stream, Wih1, fciW, ws);
    hipLaunchKernelGGL(prep_frags, dim3(340), dim3(256), 0, stream,
                       Whh1, Wih2, Whh2, Wih3, Whh3, fcoW, ws);
    hipLaunchKernelGGL(prep_input, dim3(kB), dim3(256), 0, stream,
                       enc, bn_g, bn_b, bn_m, bn_v, fcib, bih1, ws);
    hipLaunchKernelGGL(gru_main, dim3(NWG), dim3(1024), 0, stream,
                       ws, h1in, h2in, h3in, bhh1, bih2, bhh2, bih3, bhh3, fcob, out);
}